// Round 1
// baseline (1058.576 us; speedup 1.0000x reference)
//
#include <hip/hip_runtime.h>

// DGP-RF embeddings, fused MFMA implementation.
// Pipeline per workgroup (256 thr = 4 waves, 32-point tile, 4096 WGs):
//   stage X tile (and X^2) as bf16 in LDS ->
//   for each 128-wide RF chunk: GEMM1 (m,v) via mfma_f32_16x16x32_bf16,
//     exact ReLU moments in registers, round-trip m',v',m'^2+v' through LDS
//     (C-layout -> A-layout), GEMM2 accumulate (mo, vo) ->
//   epilogue: prec = 1/vo, atomicAdd into d_out halves (sum prec*mo, sum prec).
// Then finalize kernel: means = pm/p, vars = 1/p.

#define NPTS   131072
#define SGRP   16384
#define DIN    256
#define NRF    1024
#define DOUT   128

#define XLD    264   // 256 + 8 pad (keeps 16B row alignment, 2-way-max bank alias)
#define TLD    136   // 128 + 8 pad

typedef __attribute__((ext_vector_type(8))) short bf16x8;
typedef __attribute__((ext_vector_type(4))) float f32x4;

__device__ __forceinline__ unsigned short f2bf(float f) {
  unsigned u = __float_as_uint(f);
  u += 0x7fffu + ((u >> 16) & 1u);   // round-to-nearest-even
  return (unsigned short)(u >> 16);
}

__device__ __forceinline__ float fast_rcp(float x) {
#if __has_builtin(__builtin_amdgcn_rcpf)
  return __builtin_amdgcn_rcpf(x);
#else
  return 1.0f / x;
#endif
}
__device__ __forceinline__ float fast_rsq(float x) {
#if __has_builtin(__builtin_amdgcn_rsqf)
  return __builtin_amdgcn_rsqf(x);
#else
  return rsqrtf(x);
#endif
}
__device__ __forceinline__ float fast_exp2(float x) {
#if __has_builtin(__builtin_amdgcn_exp2f)
  return __builtin_amdgcn_exp2f(x);
#else
  return exp2f(x);
#endif
}

// Exact Gaussian-ReLU moments. Phi via Abramowitz-Stegun 7.1.26 (|err|<1.5e-7),
// sharing one exp2 between erf tail and the pdf: exp(-x^2)|x=z/sqrt2 == exp(-z^2/2).
__device__ __forceinline__ void relu_moments(float mu, float v,
                                             float& mo, float& vo, float& t3) {
  float vpe = v + 1e-8f;
  float rsq = fast_rsq(vpe);
  float s   = vpe * rsq;
  float z   = mu * rsq;
  float E   = fast_exp2(-0.7213475204444817f * z * z);  // exp(-z^2/2)
  float x   = 0.70710678118654752f * fabsf(z);
  float t   = fast_rcp(fmaf(0.3275911f, x, 1.0f));
  float poly = t * fmaf(t, fmaf(t, fmaf(t, fmaf(t, 1.061405429f, -1.453152027f),
                                        1.421413741f), -0.284496736f), 0.254829592f);
  float q   = 0.5f * poly * E;
  float Phi = (z >= 0.0f) ? (1.0f - q) : q;
  float phi = 0.3989422804014327f * E;
  float sphi = s * phi;
  mo = fmaf(mu, Phi, sphi);
  float ey2 = fmaf(fmaf(mu, mu, v), Phi, mu * sphi);
  vo = fmaxf(fmaf(-mo, mo, ey2), 1e-6f);
  t3 = fmaf(mo, mo, vo);
}

// ---------------- kernel 0: detect whether X_idx is int32 or int64 -------------
__global__ void detect_idx_kernel(const unsigned* __restrict__ raw,
                                  int* __restrict__ flag) {
  __shared__ int any_nz;
  if (threadIdx.x == 0) any_nz = 0;
  __syncthreads();
  // If the buffer is int64, every high word is 0. If int32 (random permutation
  // of 0..16383), 256 consecutive odd words being all-zero is impossible.
  if (raw[2 * threadIdx.x + 1] != 0u) atomicOr(&any_nz, 1);
  __syncthreads();
  if (threadIdx.x == 0) *flag = (any_nz == 0) ? 1 : 0;   // 1 => int64
}

// ---------------- kernel 1: convert weights to bf16 (plus W2_mu^2) -------------
__global__ __launch_bounds__(256) void convert_kernel(
    const float* __restrict__ W1mu, const float* __restrict__ W1var,
    const float* __restrict__ W2mu, const float* __restrict__ W2var,
    unsigned short* __restrict__ w1mu_bf, unsigned short* __restrict__ w1var_bf,
    unsigned short* __restrict__ w2mu_bf, unsigned short* __restrict__ w2musq_bf,
    unsigned short* __restrict__ w2var_bf) {
  int i = blockIdx.x * 256 + threadIdx.x;      // grid covers 262144 exactly
  w1mu_bf[i]  = f2bf(W1mu[i]);
  w1var_bf[i] = f2bf(W1var[i]);
  if (i < NRF * DOUT) {
    float m = W2mu[i];
    w2mu_bf[i]   = f2bf(m);
    w2musq_bf[i] = f2bf(m * m);
    w2var_bf[i]  = f2bf(W2var[i]);
  }
}

// ---------------- kernel 2: fused DGP-RF block --------------------------------
__global__ __launch_bounds__(256) void fused_kernel(
    const float* __restrict__ X,
    const unsigned* __restrict__ Xidx_raw,
    const unsigned short* __restrict__ W1mu, const unsigned short* __restrict__ W1var,
    const unsigned short* __restrict__ W2mu, const unsigned short* __restrict__ W2musq,
    const unsigned short* __restrict__ W2var,
    const int* __restrict__ flag64,
    float* __restrict__ acc_means,   // [S,128] accumulates prec*mo
    float* __restrict__ acc_vars) {  // [S,128] accumulates prec
  __shared__ unsigned short Xb[32 * XLD];
  __shared__ unsigned short Xq[32 * XLD];
  __shared__ unsigned short Tm[32 * TLD];
  __shared__ unsigned short Tv[32 * TLD];
  __shared__ unsigned short T3[32 * TLD];
  __shared__ int sidx[32];

  const int tid = threadIdx.x;
  const int p0  = blockIdx.x * 32;
  const int is64 = *flag64;

  if (tid < 32) {
    int p = p0 + tid;
    // low word suffices either way (indices < 16384)
    sidx[tid] = (int)(is64 ? Xidx_raw[2 * (size_t)p] : Xidx_raw[p]);
  }
  // stage X tile as bf16 (and elementwise square), 8 float4 per thread
#pragma unroll
  for (int i = 0; i < 8; ++i) {
    int idx4 = i * 256 + tid;       // 0..2047 (32 rows x 64 float4)
    int row  = idx4 >> 6;
    int c4   = idx4 & 63;
    float4 xv = *(const float4*)(X + (size_t)(p0 + row) * DIN + c4 * 4);
    int off = row * XLD + c4 * 4;
    ushort4 b, q;
    b.x = f2bf(xv.x); b.y = f2bf(xv.y); b.z = f2bf(xv.z); b.w = f2bf(xv.w);
    q.x = f2bf(xv.x * xv.x); q.y = f2bf(xv.y * xv.y);
    q.z = f2bf(xv.z * xv.z); q.w = f2bf(xv.w * xv.w);
    *(ushort4*)(Xb + off) = b;
    *(ushort4*)(Xq + off) = q;
  }
  __syncthreads();

  const int lane = tid & 63;
  const int wave = tid >> 6;
  const int l16  = lane & 15;
  const int quad = lane >> 4;

  f32x4 acc_mo[2][2], acc_vo[2][2];
#pragma unroll
  for (int mt = 0; mt < 2; ++mt)
#pragma unroll
    for (int j = 0; j < 2; ++j) {
      acc_mo[mt][j] = (f32x4){0.f, 0.f, 0.f, 0.f};
      acc_vo[mt][j] = (f32x4){0.f, 0.f, 0.f, 0.f};
    }

#pragma unroll 1
  for (int c = 0; c < 8; ++c) {
    // ---- layer 1: m,v chunk [32 x 128] ----
    f32x4 am[2][2], av[2][2];
#pragma unroll
    for (int mt = 0; mt < 2; ++mt)
#pragma unroll
      for (int nt = 0; nt < 2; ++nt) {
        am[mt][nt] = (f32x4){0.f, 0.f, 0.f, 0.f};
        av[mt][nt] = (f32x4){0.f, 0.f, 0.f, 0.f};
      }
#pragma unroll
    for (int k = 0; k < 8; ++k) {
      bf16x8 bmu[2], bvr[2];
#pragma unroll
      for (int nt = 0; nt < 2; ++nt) {
        int n = c * 128 + (wave * 2 + nt) * 16 + l16;
        size_t off = (size_t)n * DIN + k * 32 + quad * 8;
        bmu[nt] = *(const bf16x8*)(W1mu + off);
        bvr[nt] = *(const bf16x8*)(W1var + off);
      }
#pragma unroll
      for (int mt = 0; mt < 2; ++mt) {
        int aoff = (mt * 16 + l16) * XLD + k * 32 + quad * 8;
        bf16x8 ax = *(const bf16x8*)(Xb + aoff);
        bf16x8 aq = *(const bf16x8*)(Xq + aoff);
#pragma unroll
        for (int nt = 0; nt < 2; ++nt) {
          am[mt][nt] = __builtin_amdgcn_mfma_f32_16x16x32_bf16(ax, bmu[nt], am[mt][nt], 0, 0, 0);
          av[mt][nt] = __builtin_amdgcn_mfma_f32_16x16x32_bf16(aq, bvr[nt], av[mt][nt], 0, 0, 0);
        }
      }
    }
    // ---- ReLU moments, write m', v', m'^2+v' to LDS (C-layout -> A-layout) ----
#pragma unroll
    for (int mt = 0; mt < 2; ++mt)
#pragma unroll
      for (int nt = 0; nt < 2; ++nt) {
        int col = (wave * 2 + nt) * 16 + l16;
#pragma unroll
        for (int r = 0; r < 4; ++r) {
          float mo, vo, t3;
          relu_moments(am[mt][nt][r], av[mt][nt][r], mo, vo, t3);
          int row = mt * 16 + quad * 4 + r;
          int o = row * TLD + col;
          Tm[o] = f2bf(mo); Tv[o] = f2bf(vo); T3[o] = f2bf(t3);
        }
      }
    __syncthreads();
    // ---- layer 2: accumulate mo,vo over this chunk's 128 RFs ----
#pragma unroll
    for (int k2 = 0; k2 < 4; ++k2) {
      bf16x8 b2m[2], b2s[2], b2v[2];
#pragma unroll
      for (int j = 0; j < 2; ++j) {
        int n = (wave * 2 + j) * 16 + l16;
        size_t off = (size_t)n * NRF + c * 128 + k2 * 32 + quad * 8;
        b2m[j] = *(const bf16x8*)(W2mu + off);
        b2s[j] = *(const bf16x8*)(W2musq + off);
        b2v[j] = *(const bf16x8*)(W2var + off);
      }
#pragma unroll
      for (int mt = 0; mt < 2; ++mt) {
        int aoff = (mt * 16 + l16) * TLD + k2 * 32 + quad * 8;
        bf16x8 fam = *(const bf16x8*)(Tm + aoff);
        bf16x8 fav = *(const bf16x8*)(Tv + aoff);
        bf16x8 fa3 = *(const bf16x8*)(T3 + aoff);
#pragma unroll
        for (int j = 0; j < 2; ++j) {
          acc_mo[mt][j] = __builtin_amdgcn_mfma_f32_16x16x32_bf16(fam, b2m[j], acc_mo[mt][j], 0, 0, 0);
          acc_vo[mt][j] = __builtin_amdgcn_mfma_f32_16x16x32_bf16(fav, b2s[j], acc_vo[mt][j], 0, 0, 0);
          acc_vo[mt][j] = __builtin_amdgcn_mfma_f32_16x16x32_bf16(fa3, b2v[j], acc_vo[mt][j], 0, 0, 0);
        }
      }
    }
    __syncthreads();
  }

  // ---- epilogue: precision-weighted scatter ----
#pragma unroll
  for (int mt = 0; mt < 2; ++mt)
#pragma unroll
    for (int j = 0; j < 2; ++j) {
      int dim = (wave * 2 + j) * 16 + l16;
#pragma unroll
      for (int r = 0; r < 4; ++r) {
        int prow = mt * 16 + quad * 4 + r;
        float mo = acc_mo[mt][j][r];
        float vo = acc_vo[mt][j][r];
        float prec = fast_rcp(vo);
        size_t o = (size_t)sidx[prow] * DOUT + dim;
        unsafeAtomicAdd(acc_means + o, prec * mo);
        unsafeAtomicAdd(acc_vars + o, prec);
      }
    }
}

// ---------------- kernel 3: finalize ------------------------------------------
__global__ __launch_bounds__(256) void finalize_kernel(float* __restrict__ means,
                                                       float* __restrict__ vars) {
  int i = blockIdx.x * 256 + threadIdx.x;   // covers S*DOUT exactly
  float p  = vars[i];
  float pm = means[i];
  float var = 1.0f / p;
  means[i] = pm * var;
  vars[i]  = var;
}

extern "C" void kernel_launch(void* const* d_in, const int* in_sizes, int n_in,
                              void* d_out, int out_size, void* d_ws, size_t ws_size,
                              hipStream_t stream) {
  const float*    X     = (const float*)d_in[0];
  const unsigned* Xidx  = (const unsigned*)d_in[1];
  const float*    W1mu  = (const float*)d_in[2];
  const float*    W1var = (const float*)d_in[3];
  const float*    W2mu  = (const float*)d_in[4];
  const float*    W2var = (const float*)d_in[5];
  float* out = (float*)d_out;

  unsigned short* w1mu_bf   = (unsigned short*)d_ws;
  unsigned short* w1var_bf  = w1mu_bf + NRF * DIN;       // 262144
  unsigned short* w2mu_bf   = w1var_bf + NRF * DIN;
  unsigned short* w2musq_bf = w2mu_bf + NRF * DOUT;      // 131072
  unsigned short* w2var_bf  = w2musq_bf + NRF * DOUT;
  int* flag = (int*)(w2var_bf + NRF * DOUT);

  hipMemsetAsync(d_out, 0, (size_t)out_size * sizeof(float), stream);
  detect_idx_kernel<<<1, 256, 0, stream>>>(Xidx, flag);
  convert_kernel<<<(NRF * DIN) / 256, 256, 0, stream>>>(
      W1mu, W1var, W2mu, W2var, w1mu_bf, w1var_bf, w2mu_bf, w2musq_bf, w2var_bf);
  fused_kernel<<<NPTS / 32, 256, 0, stream>>>(
      X, Xidx, w1mu_bf, w1var_bf, w2mu_bf, w2musq_bf, w2var_bf, flag,
      out, out + (size_t)SGRP * DOUT);
  finalize_kernel<<<(SGRP * DOUT) / 256, 256, 0, stream>>>(
      out, out + (size_t)SGRP * DOUT);
}